// Round 8
// baseline (1267.548 us; speedup 1.0000x reference)
//
#include <hip/hip_runtime.h>
#include <cstddef>

// Problem constants
#define B_  2
#define S_  2048
#define D_  1024
#define L_  4
#define H_  16
#define HD_ 64
#define MLP_ 4096
#define EPS_ 1e-5f

typedef __attribute__((ext_vector_type(8))) short  bf16x8;
typedef __attribute__((ext_vector_type(4))) float  f32x4;

__device__ __forceinline__ unsigned short f2bf(float x) {
    unsigned int u = __float_as_uint(x);
    u = (u + 0x7fffu + ((u >> 16) & 1u)) >> 16;
    return (unsigned short)u;
}
__device__ __forceinline__ float bf2f(unsigned short h) {
    return __uint_as_float(((unsigned int)h) << 16);
}

// ---------------------------------------------------------------------------
// Elementwise fp32 -> hi/lo bf16 split (layout-preserving).
// ---------------------------------------------------------------------------
__global__ __launch_bounds__(256) void aconv_kernel(
    const float* __restrict__ X, unsigned short* __restrict__ Xh,
    unsigned short* __restrict__ Xl)
{
    const size_t i4 = (size_t)blockIdx.x * 256 + threadIdx.x;
    const float4 v = *(const float4*)(X + i4 * 4);
    ushort4 h, l;
    h.x = f2bf(v.x); l.x = f2bf(v.x - bf2f(h.x));
    h.y = f2bf(v.y); l.y = f2bf(v.y - bf2f(h.y));
    h.z = f2bf(v.z); l.z = f2bf(v.z - bf2f(h.z));
    h.w = f2bf(v.w); l.w = f2bf(v.w - bf2f(h.w));
    *(ushort4*)(Xh + i4 * 4) = h;
    *(ushort4*)(Xl + i4 * 4) = l;
}

// ---------------------------------------------------------------------------
// Weight transpose+split: W[K][N] fp32 -> Thi/Tlo[N][K] bf16 bits.
// ---------------------------------------------------------------------------
__global__ __launch_bounds__(256) void wconv_kernel(
    const float* __restrict__ W, unsigned short* __restrict__ Thi,
    unsigned short* __restrict__ Tlo, int K, int N)
{
    __shared__ float T[32][33];
    const int n0 = blockIdx.x * 32, k0 = blockIdx.y * 32;
    const int t = threadIdx.x;
    {
        const int r = t >> 3, c4 = (t & 7) * 4;
        const float4 w = *(const float4*)(W + (size_t)(k0 + r) * N + n0 + c4);
        T[r][c4 + 0] = w.x; T[r][c4 + 1] = w.y;
        T[r][c4 + 2] = w.z; T[r][c4 + 3] = w.w;
    }
    __syncthreads();
    {
        const int n = t >> 3, k4 = (t & 7) * 4;
        ushort4 h, l;
        float f;
        f = T[k4 + 0][n]; h.x = f2bf(f); l.x = f2bf(f - bf2f(h.x));
        f = T[k4 + 1][n]; h.y = f2bf(f); l.y = f2bf(f - bf2f(h.y));
        f = T[k4 + 2][n]; h.z = f2bf(f); l.z = f2bf(f - bf2f(h.z));
        f = T[k4 + 3][n]; h.w = f2bf(f); l.w = f2bf(f - bf2f(h.w));
        *(ushort4*)(Thi + (size_t)(n0 + n) * K + k0 + k4) = h;
        *(ushort4*)(Tlo + (size_t)(n0 + n) * K + k0 + k4) = l;
    }
}

// ---------------------------------------------------------------------------
// Split-bf16 MFMA GEMM, PRE-SPLIT A: C = act(A @ W + bias)
// Ah/Al: [M][K] bf16, Bth/Btl: [N][K] bf16. 3-term MFMA (validated r5).
// EPI: 0 none, 1 relu, 2 gelu. OUT: 0 fp32 C; 1 bf16 hi/lo (Chi/Clo).
// ---------------------------------------------------------------------------
template <int EPI, int OUT>
__global__ __launch_bounds__(256) void gemm_bf16p_kernel(
    const unsigned short* __restrict__ Ah, const unsigned short* __restrict__ Al,
    const unsigned short* __restrict__ Bth, const unsigned short* __restrict__ Btl,
    const float* __restrict__ bias, float* __restrict__ C,
    unsigned short* __restrict__ Chi, unsigned short* __restrict__ Clo,
    int M, int N, int K)
{
    __shared__ unsigned short As_hi[128 * 40];
    __shared__ unsigned short As_lo[128 * 40];
    __shared__ unsigned short Bs_hi[128 * 40];
    __shared__ unsigned short Bs_lo[128 * 40];

    const int tid  = threadIdx.x;
    const int lane = tid & 63;
    const int wid  = tid >> 6;
    const int wr   = wid >> 1, wc = wid & 1;
    const int l15  = lane & 15, chunk = lane >> 4;
    const int row0 = blockIdx.y * 128;
    const int col0 = blockIdx.x * 128;

    const int a_off = (wr * 64 + l15) * 40 + chunk * 8;
    const int b_off = (wc * 64 + l15) * 40 + chunk * 8;

    f32x4 acc[4][4] = {};

    for (int k0 = 0; k0 < K; k0 += 32) {
        __syncthreads();
        #pragma unroll
        for (int u = 0; u < 2; ++u) {
            const int idx = tid + u * 256;      // 0..511
            const int r  = idx >> 2;            // 0..127
            const int kc = (idx & 3) * 8;       // 0..24
            const size_t ga = (size_t)(row0 + r) * K + k0 + kc;
            *(uint4*)&As_hi[r * 40 + kc] = *(const uint4*)(Ah + ga);
            *(uint4*)&As_lo[r * 40 + kc] = *(const uint4*)(Al + ga);
            const size_t gb = (size_t)(col0 + r) * K + k0 + kc;
            *(uint4*)&Bs_hi[r * 40 + kc] = *(const uint4*)(Bth + gb);
            *(uint4*)&Bs_lo[r * 40 + kc] = *(const uint4*)(Btl + gb);
        }
        __syncthreads();

        bf16x8 ah[4], al[4], bh[4], bl[4];
        #pragma unroll
        for (int mi = 0; mi < 4; ++mi) {
            ah[mi] = *(const bf16x8*)&As_hi[a_off + mi * 640];
            al[mi] = *(const bf16x8*)&As_lo[a_off + mi * 640];
        }
        #pragma unroll
        for (int ni = 0; ni < 4; ++ni) {
            bh[ni] = *(const bf16x8*)&Bs_hi[b_off + ni * 640];
            bl[ni] = *(const bf16x8*)&Bs_lo[b_off + ni * 640];
        }
        __builtin_amdgcn_s_setprio(1);
        #pragma unroll
        for (int mi = 0; mi < 4; ++mi)
            #pragma unroll
            for (int ni = 0; ni < 4; ++ni) {
                acc[mi][ni] = __builtin_amdgcn_mfma_f32_16x16x32_bf16(
                    ah[mi], bh[ni], acc[mi][ni], 0, 0, 0);
                acc[mi][ni] = __builtin_amdgcn_mfma_f32_16x16x32_bf16(
                    ah[mi], bl[ni], acc[mi][ni], 0, 0, 0);
                acc[mi][ni] = __builtin_amdgcn_mfma_f32_16x16x32_bf16(
                    al[mi], bh[ni], acc[mi][ni], 0, 0, 0);
            }
        __builtin_amdgcn_s_setprio(0);
    }

    const int rbase = row0 + wr * 64 + (lane >> 4) * 4;
    const int cbase = col0 + wc * 64 + l15;
    #pragma unroll
    for (int mi = 0; mi < 4; ++mi) {
        #pragma unroll
        for (int reg = 0; reg < 4; ++reg) {
            const int gr = rbase + mi * 16 + reg;
            #pragma unroll
            for (int ni = 0; ni < 4; ++ni) {
                const int gc = cbase + ni * 16;
                float v = acc[mi][ni][reg] + bias[gc];
                if (EPI == 1) v = fmaxf(v, 0.f);
                else if (EPI == 2) v = 0.5f * v * (1.f + erff(v * 0.70710678118654752f));
                if (OUT == 0) {
                    C[(size_t)gr * N + gc] = v;
                } else {
                    const unsigned short hv = f2bf(v);
                    Chi[(size_t)gr * N + gc] = hv;
                    Clo[(size_t)gr * N + gc] = f2bf(v - bf2f(hv));
                }
            }
        }
    }
}

// ---------------------------------------------------------------------------
// Split-bf16 MFMA GEMM, fp32 A converted in-loop (round-5 validated;
// fallback when workspace is too small for the LO pre-split).
// ---------------------------------------------------------------------------
template <int EPI>
__global__ __launch_bounds__(256) void gemm_bf16s_kernel(
    const float* __restrict__ A,
    const unsigned short* __restrict__ Bth, const unsigned short* __restrict__ Btl,
    const float* __restrict__ bias, float* __restrict__ C,
    int M, int N, int K)
{
    __shared__ unsigned short As_hi[128 * 40];
    __shared__ unsigned short As_lo[128 * 40];
    __shared__ unsigned short Bs_hi[128 * 40];
    __shared__ unsigned short Bs_lo[128 * 40];

    const int tid  = threadIdx.x;
    const int lane = tid & 63;
    const int wid  = tid >> 6;
    const int wr   = wid >> 1, wc = wid & 1;
    const int l15  = lane & 15, chunk = lane >> 4;
    const int row0 = blockIdx.y * 128;
    const int col0 = blockIdx.x * 128;

    const int a_off = (wr * 64 + l15) * 40 + chunk * 8;
    const int b_off = (wc * 64 + l15) * 40 + chunk * 8;

    f32x4 acc[4][4] = {};

    for (int k0 = 0; k0 < K; k0 += 32) {
        __syncthreads();
        #pragma unroll
        for (int u = 0; u < 4; ++u) {
            const int idx = tid + u * 256;
            const int r  = idx >> 3;
            const int kc = (idx & 7) * 4;
            const float4 a = *(const float4*)(A + (size_t)(row0 + r) * K + k0 + kc);
            ushort4 h, l;
            h.x = f2bf(a.x); l.x = f2bf(a.x - bf2f(h.x));
            h.y = f2bf(a.y); l.y = f2bf(a.y - bf2f(h.y));
            h.z = f2bf(a.z); l.z = f2bf(a.z - bf2f(h.z));
            h.w = f2bf(a.w); l.w = f2bf(a.w - bf2f(h.w));
            *(ushort4*)&As_hi[r * 40 + kc] = h;
            *(ushort4*)&As_lo[r * 40 + kc] = l;
        }
        #pragma unroll
        for (int u = 0; u < 2; ++u) {
            const int idx = tid + u * 256;
            const int c  = idx >> 2;
            const int kc = (idx & 3) * 8;
            const size_t gb = (size_t)(col0 + c) * K + k0 + kc;
            *(uint4*)&Bs_hi[c * 40 + kc] = *(const uint4*)(Bth + gb);
            *(uint4*)&Bs_lo[c * 40 + kc] = *(const uint4*)(Btl + gb);
        }
        __syncthreads();

        bf16x8 ah[4], al[4], bh[4], bl[4];
        #pragma unroll
        for (int mi = 0; mi < 4; ++mi) {
            ah[mi] = *(const bf16x8*)&As_hi[a_off + mi * 640];
            al[mi] = *(const bf16x8*)&As_lo[a_off + mi * 640];
        }
        #pragma unroll
        for (int ni = 0; ni < 4; ++ni) {
            bh[ni] = *(const bf16x8*)&Bs_hi[b_off + ni * 640];
            bl[ni] = *(const bf16x8*)&Bs_lo[b_off + ni * 640];
        }
        #pragma unroll
        for (int mi = 0; mi < 4; ++mi)
            #pragma unroll
            for (int ni = 0; ni < 4; ++ni) {
                acc[mi][ni] = __builtin_amdgcn_mfma_f32_16x16x32_bf16(
                    ah[mi], bh[ni], acc[mi][ni], 0, 0, 0);
                acc[mi][ni] = __builtin_amdgcn_mfma_f32_16x16x32_bf16(
                    ah[mi], bl[ni], acc[mi][ni], 0, 0, 0);
                acc[mi][ni] = __builtin_amdgcn_mfma_f32_16x16x32_bf16(
                    al[mi], bh[ni], acc[mi][ni], 0, 0, 0);
            }
    }

    const int rbase = row0 + wr * 64 + (lane >> 4) * 4;
    const int cbase = col0 + wc * 64 + l15;
    #pragma unroll
    for (int mi = 0; mi < 4; ++mi) {
        #pragma unroll
        for (int reg = 0; reg < 4; ++reg) {
            const int gr = rbase + mi * 16 + reg;
            #pragma unroll
            for (int ni = 0; ni < 4; ++ni) {
                const int gc = cbase + ni * 16;
                float v = acc[mi][ni][reg] + bias[gc];
                if (EPI == 1) v = fmaxf(v, 0.f);
                else if (EPI == 2) v = 0.5f * v * (1.f + erff(v * 0.70710678118654752f));
                C[(size_t)gr * N + gc] = v;
            }
        }
    }
}

// ---------------------------------------------------------------------------
// NS[b,s,:] = sum_l normalize(layer_outputs[b,l,s,:])
// ---------------------------------------------------------------------------
__global__ __launch_bounds__(256) void grn_ns_kernel(
    const float* __restrict__ LO, float* __restrict__ NS)
{
    const int row = blockIdx.x;
    const int b = row >> 11, s = row & (S_ - 1);
    const int tid = threadIdx.x;
    __shared__ float r1[4], r2[4];

    float acc[4] = {0.f, 0.f, 0.f, 0.f};
    #pragma unroll
    for (int l = 0; l < L_; ++l) {
        const float* xr = LO + ((size_t)((b * L_ + l) * S_ + s)) * D_;
        const float4 v = *(const float4*)(xr + tid * 4);
        float s1 = v.x + v.y + v.z + v.w;
        float s2 = v.x * v.x + v.y * v.y + v.z * v.z + v.w * v.w;
        #pragma unroll
        for (int off = 32; off >= 1; off >>= 1) {
            s1 += __shfl_xor(s1, off);
            s2 += __shfl_xor(s2, off);
        }
        if ((tid & 63) == 0) { r1[tid >> 6] = s1; r2[tid >> 6] = s2; }
        __syncthreads();
        s1 = r1[0] + r1[1] + r1[2] + r1[3];
        s2 = r2[0] + r2[1] + r2[2] + r2[3];
        __syncthreads();
        const float mu  = s1 * (1.f / D_);
        const float var = s2 * (1.f / D_) - mu * mu;
        const float rs  = rsqrtf(var + EPS_);
        acc[0] += (v.x - mu) * rs;
        acc[1] += (v.y - mu) * rs;
        acc[2] += (v.z - mu) * rs;
        acc[3] += (v.w - mu) * rs;
    }
    float4 o = {acc[0], acc[1], acc[2], acc[3]};
    *(float4*)(NS + (size_t)row * D_ + tid * 4) = o;
}

// ---------------------------------------------------------------------------
// out[b,s,d] = sum_l P[(b,l,s),d] + NS[b,s,d]*g[d] + 4*be[d]
// ---------------------------------------------------------------------------
__global__ __launch_bounds__(256) void grn_reduce_kernel(
    const float* __restrict__ P, const float* __restrict__ NS,
    const float* __restrict__ g, const float* __restrict__ be,
    float* __restrict__ out)
{
    const size_t i4 = (size_t)blockIdx.x * 256 + threadIdx.x;
    const int d4 = (int)(i4 & (D_ / 4 - 1));
    const size_t row = i4 >> 8;
    const int b = (int)(row >> 11), s = (int)(row & (S_ - 1));

    float4 a = {0.f, 0.f, 0.f, 0.f};
    #pragma unroll
    for (int l = 0; l < L_; ++l) {
        const float4 w = *(const float4*)(P + ((size_t)((b * L_ + l) * S_ + s)) * D_ + d4 * 4);
        a.x += w.x; a.y += w.y; a.z += w.z; a.w += w.w;
    }
    const float4 n  = *(const float4*)(NS + row * D_ + d4 * 4);
    const float4 gg = *(const float4*)(g + d4 * 4);
    const float4 bb = *(const float4*)(be + d4 * 4);
    float4 o;
    o.x = a.x + n.x * gg.x + 4.f * bb.x;
    o.y = a.y + n.y * gg.y + 4.f * bb.y;
    o.z = a.z + n.z * gg.z + 4.f * bb.z;
    o.w = a.w + n.w * gg.w + 4.f * bb.w;
    *(float4*)(out + row * D_ + d4 * 4) = o;
}

// ---------------------------------------------------------------------------
// K/V split pre-pass: K -> Kh/Kl[bh][s][d]; V -> Vth/Vtl[bh][d][s].
// ---------------------------------------------------------------------------
__global__ __launch_bounds__(256) void kvconv_kernel(
    const float* __restrict__ Kin, const float* __restrict__ Vin,
    unsigned short* __restrict__ Kh, unsigned short* __restrict__ Kl,
    unsigned short* __restrict__ Vth, unsigned short* __restrict__ Vtl)
{
    __shared__ float T[64][68];
    const int t = threadIdx.x;
    const int st = blockIdx.x;
    const int bh = blockIdx.y;
    const int b = bh >> 4, h = bh & 15;
    const int s0 = st * 64;

    #pragma unroll
    for (int u = 0; u < 4; ++u) {
        const int idx = t + u * 256;
        const int r  = idx >> 4;
        const int c4 = (idx & 15) * 4;
        const size_t src = ((size_t)(b * S_ + s0 + r)) * D_ + h * 64 + c4;
        const float4 kf = *(const float4*)(Kin + src);
        ushort4 hh, ll;
        hh.x = f2bf(kf.x); ll.x = f2bf(kf.x - bf2f(hh.x));
        hh.y = f2bf(kf.y); ll.y = f2bf(kf.y - bf2f(hh.y));
        hh.z = f2bf(kf.z); ll.z = f2bf(kf.z - bf2f(hh.z));
        hh.w = f2bf(kf.w); ll.w = f2bf(kf.w - bf2f(hh.w));
        const size_t kd = ((size_t)bh * S_ + s0 + r) * 64 + c4;
        *(ushort4*)(Kh + kd) = hh;
        *(ushort4*)(Kl + kd) = ll;
        const float4 vf = *(const float4*)(Vin + src);
        T[r][c4 + 0] = vf.x; T[r][c4 + 1] = vf.y;
        T[r][c4 + 2] = vf.z; T[r][c4 + 3] = vf.w;
    }
    __syncthreads();
    #pragma unroll
    for (int u = 0; u < 4; ++u) {
        const int idx = t + u * 256;
        const int d  = idx >> 4;
        const int s4 = (idx & 15) * 4;
        ushort4 hh, ll;
        float f;
        f = T[s4 + 0][d]; hh.x = f2bf(f); ll.x = f2bf(f - bf2f(hh.x));
        f = T[s4 + 1][d]; hh.y = f2bf(f); ll.y = f2bf(f - bf2f(hh.y));
        f = T[s4 + 2][d]; hh.z = f2bf(f); ll.z = f2bf(f - bf2f(hh.z));
        f = T[s4 + 3][d]; hh.w = f2bf(f); ll.w = f2bf(f - bf2f(hh.w));
        const size_t vd = ((size_t)bh * 64 + d) * S_ + s0 + s4;
        *(ushort4*)(Vth + vd) = hh;
        *(ushort4*)(Vtl + vd) = ll;
    }
}

// ---------------------------------------------------------------------------
// Split-bf16 MFMA flash attention. P quantized to bf16-hi only for PV
// (32 MFMA/tile), setprio around MFMA clusters.
// ---------------------------------------------------------------------------
__global__ __launch_bounds__(256) void attn_mfma_kernel(
    const float* __restrict__ Q,
    const unsigned short* __restrict__ Kh, const unsigned short* __restrict__ Kl,
    const unsigned short* __restrict__ Vth, const unsigned short* __restrict__ Vtl,
    float* __restrict__ O)
{
    __shared__ unsigned short Ksh[64 * 72], Ksl[64 * 72];   // [key][d]
    __shared__ unsigned short Vsh[64 * 72], Vsl[64 * 72];   // [d][key]
    __shared__ unsigned short Phs[4][32 * 72];              // per-wave [q][key]

    const int tid  = threadIdx.x;
    const int lane = tid & 63;
    const int w    = tid >> 6;
    const int l15  = lane & 15, g = lane >> 4;
    const int bh   = blockIdx.y;
    const int b    = bh >> 4, h = bh & 15;
    const int q0   = blockIdx.x * 128 + w * 32;
    const float scale = 0.125f;

    bf16x8 qh[2][2], ql[2][2];
    #pragma unroll
    for (int mi = 0; mi < 2; ++mi)
        #pragma unroll
        for (int ks = 0; ks < 2; ++ks) {
            const float* qp = Q + ((size_t)(b * S_ + q0 + mi * 16 + l15)) * D_
                              + h * 64 + ks * 32 + g * 8;
            const float4 f0 = *(const float4*)qp;
            const float4 f1 = *(const float4*)(qp + 4);
            const float vs[8] = {f0.x * scale, f0.y * scale, f0.z * scale, f0.w * scale,
                                 f1.x * scale, f1.y * scale, f1.z * scale, f1.w * scale};
            #pragma unroll
            for (int j = 0; j < 8; ++j) {
                const unsigned short hv = f2bf(vs[j]);
                qh[mi][ks][j] = (short)hv;
                ql[mi][ks][j] = (short)f2bf(vs[j] - bf2f(hv));
            }
        }

    f32x4 o[2][4] = {};
    float mrun[2][4], lrun[2][4];
    #pragma unroll
    for (int mi = 0; mi < 2; ++mi)
        #pragma unroll
        for (int r = 0; r < 4; ++r) { mrun[mi][r] = -1e30f; lrun[mi][r] = 0.f; }

    const unsigned short* KhB = Kh  + (size_t)bh * S_ * 64;
    const unsigned short* KlB = Kl  + (size_t)bh * S_ * 64;
    const unsigned short* VhB = Vth + (size_t)bh * 64 * S_;
    const unsigned short* VlB = Vtl + (size_t)bh * 64 * S_;

    for (int kt = 0; kt < S_; kt += 64) {
        __syncthreads();
        #pragma unroll
        for (int u = 0; u < 2; ++u) {
            const int idx = tid + u * 256;
            const int rr  = idx >> 3;
            const int c8  = (idx & 7) * 8;
            *(uint4*)&Ksh[rr * 72 + c8] = *(const uint4*)(KhB + (size_t)(kt + rr) * 64 + c8);
            *(uint4*)&Ksl[rr * 72 + c8] = *(const uint4*)(KlB + (size_t)(kt + rr) * 64 + c8);
            *(uint4*)&Vsh[rr * 72 + c8] = *(const uint4*)(VhB + (size_t)rr * S_ + kt + c8);
            *(uint4*)&Vsl[rr * 72 + c8] = *(const uint4*)(VlB + (size_t)rr * S_ + kt + c8);
        }
        __syncthreads();

        // ---- scores
        f32x4 s[2][4] = {};
        #pragma unroll
        for (int ks = 0; ks < 2; ++ks)
            #pragma unroll
            for (int ni = 0; ni < 4; ++ni) {
                const bf16x8 khf = *(const bf16x8*)&Ksh[(ni * 16 + l15) * 72 + ks * 32 + g * 8];
                const bf16x8 klf = *(const bf16x8*)&Ksl[(ni * 16 + l15) * 72 + ks * 32 + g * 8];
                __builtin_amdgcn_s_setprio(1);
                #pragma unroll
                for (int mi = 0; mi < 2; ++mi) {
                    s[mi][ni] = __builtin_amdgcn_mfma_f32_16x16x32_bf16(qh[mi][ks], khf, s[mi][ni], 0, 0, 0);
                    s[mi][ni] = __builtin_amdgcn_mfma_f32_16x16x32_bf16(qh[mi][ks], klf, s[mi][ni], 0, 0, 0);
                    s[mi][ni] = __builtin_amdgcn_mfma_f32_16x16x32_bf16(ql[mi][ks], khf, s[mi][ni], 0, 0, 0);
                }
                __builtin_amdgcn_s_setprio(0);
            }

        // ---- online softmax; P -> bf16 (hi only)
        #pragma unroll
        for (int mi = 0; mi < 2; ++mi) {
            #pragma unroll
            for (int r = 0; r < 4; ++r) {
                float mx = fmaxf(fmaxf(s[mi][0][r], s[mi][1][r]),
                                 fmaxf(s[mi][2][r], s[mi][3][r]));
                mx = fmaxf(mx, __shfl_xor(mx, 1));
                mx = fmaxf(mx, __shfl_xor(mx, 2));
                mx = fmaxf(mx, __shfl_xor(mx, 4));
                mx = fmaxf(mx, __shfl_xor(mx, 8));
                const float mn = fmaxf(mrun[mi][r], mx);
                const float c  = __expf(mrun[mi][r] - mn);
                mrun[mi][r] = mn;
                float rs = 0.f;
                #pragma unroll
                for (int ni = 0; ni < 4; ++ni) {
                    const float p = __expf(s[mi][ni][r] - mn);
                    rs += p;
                    Phs[w][(mi * 16 + 4 * g + r) * 72 + ni * 16 + l15] = f2bf(p);
                }
                rs += __shfl_xor(rs, 1);
                rs += __shfl_xor(rs, 2);
                rs += __shfl_xor(rs, 4);
                rs += __shfl_xor(rs, 8);
                lrun[mi][r] = lrun[mi][r] * c + rs;
                #pragma unroll
                for (int di = 0; di < 4; ++di) o[mi][di][r] *= c;
            }
        }

        // ---- PV (P bf16-hi only; wave-private LDS, no barrier)
        #pragma unroll
        for (int ks = 0; ks < 2; ++ks) {
            bf16x8 pfh[2];
            #pragma unroll
            for (int mi = 0; mi < 2; ++mi)
                pfh[mi] = *(const bf16x8*)&Phs[w][(mi * 16 + l15) * 72 + ks * 32 + g * 8];
            #pragma unroll
            for (int di = 0; di < 4; ++di) {
                const bf16x8 vhf = *(const bf16x8*)&Vsh[(di * 16 + l15) * 72 + ks * 32 + g * 8];
                const bf16x8 vlf = *(const bf16x8*)&Vsl[(di * 16 + l15) * 72 + ks * 32 + g * 8];
                __builtin_amdgcn_s_setprio(1);
                #pragma unroll
                for (int mi = 0; mi < 2; ++mi) {
                    o[mi][di] = __builtin_amdgcn_mfma_f32_16x16x32_bf16(pfh[mi], vhf, o[mi][di], 0, 0, 0);
                    o[mi][di] = __builtin_amdgcn_mfma_f32_16x16x32_bf16(pfh[mi], vlf, o[mi][di], 0, 0, 0);
                }
                __builtin_amdgcn_s_setprio(0);
            }
        }
    }

    #pragma unroll
    for (int mi = 0; mi < 2; ++mi)
        #pragma unroll
        for (int r = 0; r < 4; ++r) {
            const float inv = 1.f / lrun[mi][r];
            float* op = O + ((size_t)(b * S_ + q0 + mi * 16 + 4 * g + r)) * D_
                        + h * 64 + l15;
            #pragma unroll
            for (int di = 0; di < 4; ++di) op[di * 16] = o[mi][di][r] * inv;
        }
}

// ---------------------------------------------------------------------------
// out[row,:] = R[row,:] + LN(Y[row,:]) * g + beta
// ---------------------------------------------------------------------------
__global__ __launch_bounds__(256) void add_ln_kernel(
    const float* __restrict__ Y, const float* __restrict__ R,
    const float* __restrict__ g, const float* __restrict__ beta,
    float* __restrict__ out)
{
    const int row = blockIdx.x;
    const int tid = threadIdx.x;
    __shared__ float r1[4], r2[4];

    const float4 v = *(const float4*)(Y + (size_t)row * D_ + tid * 4);
    float s1 = v.x + v.y + v.z + v.w;
    float s2 = v.x * v.x + v.y * v.y + v.z * v.z + v.w * v.w;
    #pragma unroll
    for (int off = 32; off >= 1; off >>= 1) {
        s1 += __shfl_xor(s1, off);
        s2 += __shfl_xor(s2, off);
    }
    if ((tid & 63) == 0) { r1[tid >> 6] = s1; r2[tid >> 6] = s2; }
    __syncthreads();
    s1 = r1[0] + r1[1] + r1[2] + r1[3];
    s2 = r2[0] + r2[1] + r2[2] + r2[3];
    const float mu  = s1 * (1.f / D_);
    const float var = s2 * (1.f / D_) - mu * mu;
    const float rs  = rsqrtf(var + EPS_);

    const float4 rr = *(const float4*)(R + (size_t)row * D_ + tid * 4);
    const float4 gg = *(const float4*)(g + tid * 4);
    const float4 bb = *(const float4*)(beta + tid * 4);
    float4 o;
    o.x = rr.x + (v.x - mu) * rs * gg.x + bb.x;
    o.y = rr.y + (v.y - mu) * rs * gg.y + bb.y;
    o.z = rr.z + (v.z - mu) * rs * gg.z + bb.z;
    o.w = rr.w + (v.w - mu) * rs * gg.w + bb.w;
    *(float4*)(out + (size_t)row * D_ + tid * 4) = o;
}

// ---------------------------------------------------------------------------
extern "C" void kernel_launch(void* const* d_in, const int* in_sizes, int n_in,
                              void* d_out, int out_size, void* d_ws, size_t ws_size,
                              hipStream_t stream)
{
    const float* x  = (const float*)d_in[0];
    const float* LO = (const float*)d_in[1];
    const float* Wq  = (const float*)d_in[2];
    const float* bq_ = (const float*)d_in[3];
    const float* gq  = (const float*)d_in[4];
    const float* beq = (const float*)d_in[5];
    const float* Wk  = (const float*)d_in[6];
    const float* bk_ = (const float*)d_in[7];
    const float* gk  = (const float*)d_in[8];
    const float* bek = (const float*)d_in[9];
    const float* Wv  = (const float*)d_in[10];
    const float* bv_ = (const float*)d_in[11];
    const float* gv  = (const float*)d_in[12];
    const float* bev = (const float*)d_in[13];
    const float* Wo  = (const float*)d_in[14];
    const float* bo  = (const float*)d_in[15];
    const float* ang = (const float*)d_in[16];
    const float* anb = (const float*)d_in[17];
    const float* W1  = (const float*)d_in[18];
    const float* b1  = (const float*)d_in[19];
    const float* W2  = (const float*)d_in[20];
    const float* b2  = (const float*)d_in[21];
    const float* fng = (const float*)d_in[22];
    const float* fnb = (const float*)d_in[23];

    const size_t BS  = (size_t)B_ * S_;          // 4096 rows
    const size_t SEG = BS * D_;                  // 4M floats
    float* ws  = (float*)d_ws;
    float* ns   = ws;                            // NS -> attn out
    float* bufq = ws + SEG;                      // q -> attnproj out -> resid1 split
    float* bufk = ws + 2 * SEG;                  // k -> resid1
    float* bufv = ws + 3 * SEG;                  // v -> ns split -> ffn2 out
    float* big  = ws + 4 * SEG;                  // 16M f: GRN staging / KV split / FFN hidden split

    // split weights after fp32 region (at 128 MB)
    unsigned short* wt = (unsigned short*)(ws + 8 * SEG);
    const size_t MM = 1048576;
    unsigned short* wtq_h = wt;            unsigned short* wtq_l = wt + MM;
    unsigned short* wtk_h = wt + 2 * MM;   unsigned short* wtk_l = wt + 3 * MM;
    unsigned short* wtv_h = wt + 4 * MM;   unsigned short* wtv_l = wt + 5 * MM;
    unsigned short* wto_h = wt + 6 * MM;   unsigned short* wto_l = wt + 7 * MM;
    unsigned short* w1_h  = wt + 8 * MM;   unsigned short* w1_l  = wt + 12 * MM;
    unsigned short* w2_h  = wt + 16 * MM;  unsigned short* w2_l  = wt + 20 * MM;
    // optional LO split at 176 MB (needs ws_size >= 240 MB)
    unsigned short* lo_h = wt + 24 * MM;                  // 16M ushorts
    unsigned short* lo_l = lo_h + 16 * MM;                // 16M ushorts
    const bool useLoSplit = ws_size >= (size_t)252 * 1024 * 1024;

    // KV splits in big (32 MB of its 64 MB)
    const size_t KVSEG = (size_t)B_ * H_ * S_ * HD_;      // 4M elements
    unsigned short* kv  = (unsigned short*)big;
    unsigned short* kh_ = kv;
    unsigned short* kl_ = kv + KVSEG;
    unsigned short* vth = kv + 2 * KVSEG;
    unsigned short* vtl = kv + 3 * KVSEG;
    // FFN hidden split occupies big later (16M hi + 16M lo ushorts)
    unsigned short* hid_h = (unsigned short*)big;
    unsigned short* hid_l = hid_h + 16 * MM;
    // ns split lives in bufv; resid1 split lives in bufq
    unsigned short* ns_h = (unsigned short*)bufv;
    unsigned short* ns_l = ns_h + 4 * MM;
    unsigned short* r1_h = (unsigned short*)bufq;
    unsigned short* r1_l = r1_h + 4 * MM;

    const dim3 blk(256);

    // 0. weight transpose + split (+ LO split if ws allows)
    wconv_kernel<<<dim3(32, 32),  blk, 0, stream>>>(Wq, wtq_h, wtq_l, D_, D_);
    wconv_kernel<<<dim3(32, 32),  blk, 0, stream>>>(Wk, wtk_h, wtk_l, D_, D_);
    wconv_kernel<<<dim3(32, 32),  blk, 0, stream>>>(Wv, wtv_h, wtv_l, D_, D_);
    wconv_kernel<<<dim3(32, 32),  blk, 0, stream>>>(Wo, wto_h, wto_l, D_, D_);
    wconv_kernel<<<dim3(128, 32), blk, 0, stream>>>(W1, w1_h,  w1_l,  D_, MLP_);
    wconv_kernel<<<dim3(32, 128), blk, 0, stream>>>(W2, w2_h,  w2_l,  MLP_, D_);
    if (useLoSplit)
        aconv_kernel<<<dim3(16384), blk, 0, stream>>>(LO, lo_h, lo_l);

    // 1. shared normalized sum
    grn_ns_kernel<<<dim3(BS), blk, 0, stream>>>(LO, ns);

    // 2. GRN q/k/v
    const unsigned short* Wh[3] = {wtq_h, wtk_h, wtv_h};
    const unsigned short* Wl[3] = {wtq_l, wtk_l, wtv_l};
    const float* bp[3]  = {bq_, bk_, bv_};
    const float* gp[3]  = {gq, gk, gv};
    const float* bep[3] = {beq, bek, bev};
    float* outp[3] = {bufq, bufk, bufv};
    for (int p = 0; p < 3; ++p) {
        if (useLoSplit)
            gemm_bf16p_kernel<1, 0><<<dim3(D_ / 128, (B_ * L_ * S_) / 128), blk, 0, stream>>>(
                lo_h, lo_l, Wh[p], Wl[p], bp[p], big, nullptr, nullptr,
                B_ * L_ * S_, D_, D_);
        else
            gemm_bf16s_kernel<1><<<dim3(D_ / 128, (B_ * L_ * S_) / 128), blk, 0, stream>>>(
                LO, Wh[p], Wl[p], bp[p], big, B_ * L_ * S_, D_, D_);
        grn_reduce_kernel<<<dim3(BS), blk, 0, stream>>>(big, ns, gp[p], bep[p], outp[p]);
    }

    // 3. K/V split + MFMA flash attention -> ns
    kvconv_kernel<<<dim3(S_ / 64, B_ * H_), blk, 0, stream>>>(bufk, bufv, kh_, kl_, vth, vtl);
    attn_mfma_kernel<<<dim3(S_ / 128, B_ * H_), blk, 0, stream>>>(bufq, kh_, kl_, vth, vtl, ns);

    // 4. split attn-out (-> bufv, dead) then attn projection -> bufq
    aconv_kernel<<<dim3(4096), blk, 0, stream>>>(ns, ns_h, ns_l);
    gemm_bf16p_kernel<0, 0><<<dim3(D_ / 128, BS / 128), blk, 0, stream>>>(
        ns_h, ns_l, wto_h, wto_l, bo, bufq, nullptr, nullptr, (int)BS, D_, D_);

    // 5. resid1 = x + LN(attn_proj) -> bufk
    add_ln_kernel<<<dim3(BS), blk, 0, stream>>>(bufq, x, ang, anb, bufk);

    // 6. split resid1 (-> bufq, dead), FFN1 -> hidden split in big
    aconv_kernel<<<dim3(4096), blk, 0, stream>>>(bufk, r1_h, r1_l);
    gemm_bf16p_kernel<2, 1><<<dim3(MLP_ / 128, BS / 128), blk, 0, stream>>>(
        r1_h, r1_l, w1_h, w1_l, b1, nullptr, hid_h, hid_l, (int)BS, MLP_, D_);

    // 7. FFN2: hidden-split @ W2 + b2 -> bufv
    gemm_bf16p_kernel<0, 0><<<dim3(D_ / 128, BS / 128), blk, 0, stream>>>(
        hid_h, hid_l, w2_h, w2_l, b2, bufv, nullptr, nullptr, (int)BS, D_, MLP_);

    // 8. out = resid1 + LN(ffn2)
    add_ln_kernel<<<dim3(BS), blk, 0, stream>>>(bufv, bufk, fng, fnb, (float*)d_out);
}